// Round 5
// baseline (130.810 us; speedup 1.0000x reference)
//
#include <hip/hip_runtime.h>
#include <hip/hip_bf16.h>
#include <math.h>

// DETR HungarianMatcher cost matrix:
// cost[b,q,j] = 5*L1(pred_box, tgt_box) - softmax(logits)[tgt_label[j]] - 2*GIoU
// Shapes: B=16, Q=900, C=92, T=1600 -> out [B*Q, T] fp32 (92.2 MB)
//
// Round-5: TWO kernels.
//   A) softmax_kernel: -softmax(logits) -> d_ws [BQ, 92] once per row.
//      Removes per-block softmax duplication, LDS, and __syncthreads from
//      the hot kernel (rounds 2/4 both plateaued ~49 us sharing those costs).
//   B) cost_kernel: NO LDS, NO barrier. T = 1600 = 25 waves of 64 -> grid.x=25
//      is a perfect lane fit (fixes round-4's 78% tile misfit). Lane owns one
//      target in regs; wave owns 8 rows; class cost = one L1/L2 global gather
//      per row with the r*368B offset folded into the instruction immediate.

#define CC     92
#define ROWS_A 16           // rows per block, kernel A
#define RW     8            // rows per wave, kernel B
#define RR     32           // rows per block, kernel B (4 waves)

__global__ __launch_bounds__(256) void softmax_kernel(
    const float* __restrict__ logits,   // [BQ, CC]
    float*       __restrict__ nprob)    // [BQ, CC]  <- -softmax
{
    const int wv = threadIdx.x >> 6, ln = threadIdx.x & 63;
    const int base = blockIdx.x * ROWS_A;
    for (int rr = wv; rr < ROWS_A; rr += 4) {
        const long long row = base + rr;
        const float* lg = logits + row * CC;
        float v1 = (ln < CC)      ? lg[ln]      : -INFINITY;
        float v2 = (ln + 64 < CC) ? lg[ln + 64] : -INFINITY;
        float m = fmaxf(v1, v2);
        #pragma unroll
        for (int o = 32; o > 0; o >>= 1) m = fmaxf(m, __shfl_xor(m, o));
        float e1 = (ln < CC)      ? __expf(v1 - m) : 0.0f;
        float e2 = (ln + 64 < CC) ? __expf(v2 - m) : 0.0f;
        float s = e1 + e2;
        #pragma unroll
        for (int o = 32; o > 0; o >>= 1) s += __shfl_xor(s, o);
        float inv = __builtin_amdgcn_rcpf(s);
        if (ln < CC)      nprob[row * CC + ln]      = -e1 * inv;
        if (ln + 64 < CC) nprob[row * CC + ln + 64] = -e2 * inv;
    }
}

__global__ __launch_bounds__(256) void cost_kernel(
    const float* __restrict__ pboxes,   // [BQ, 4] cxcywh
    const int*   __restrict__ labels,   // [T]
    const float* __restrict__ tboxes,   // [T, 4] cxcywh
    const float* __restrict__ nprob,    // [BQ, CC] -softmax
    float*       __restrict__ out,      // [BQ, T]
    int T)
{
    const int ln = threadIdx.x & 63;
    const int wv = threadIdx.x >> 6;
    const int j    = blockIdx.x * 64 + ln;            // this lane's target
    const int row0 = blockIdx.y * RR + wv * RW;       // this wave's rows

    // ---- own target: registers for the whole kernel ----
    const float4 t = ((const float4*)tboxes)[j];      // cxcywh
    const float tx1 = t.x - 0.5f * t.z;
    const float ty1 = t.y - 0.5f * t.w;
    const float tx2 = t.x + 0.5f * t.z;
    const float ty2 = t.y + 0.5f * t.w;
    const float ta  = t.z * t.w;
    const int   lbl = labels[j];

    // per-lane base into -prob: row0 row, this lane's label column
    const float* np = nprob + (long long)row0 * CC + lbl;
    float*      op  = out   + (long long)row0 * T  + j;

    // ---- preload this wave's pred rows (L1-broadcast loads) ----
    float4 pc[RW];
    #pragma unroll
    for (int r = 0; r < RW; ++r) pc[r] = ((const float4*)pboxes)[row0 + r];

    #pragma unroll
    for (int r = 0; r < RW; ++r) {
        const float4 p = pc[r];
        const float px1 = p.x - 0.5f * p.z;
        const float py1 = p.y - 0.5f * p.w;
        const float px2 = p.x + 0.5f * p.z;
        const float py2 = p.y + 0.5f * p.w;
        const float pa  = p.z * p.w;

        // class cost gather: offset r*CC floats = r*368 B (imm-foldable)
        const float nprb = np[r * CC];

        // L1 on cxcywh
        const float l1 = fabsf(p.x - t.x) + fabsf(p.y - t.y)
                       + fabsf(p.z - t.z) + fabsf(p.w - t.w);

        // IoU
        const float iw    = fminf(px2, tx2) - fmaxf(px1, tx1);
        const float ih    = fminf(py2, ty2) - fmaxf(py1, ty1);
        const float inter = fmaxf(iw, 0.0f) * fmaxf(ih, 0.0f);
        const float uni   = pa + ta - inter;
        const float iou   = inter * __builtin_amdgcn_rcpf(uni);

        // enclosing box
        const float ew   = fmaxf(px2, tx2) - fminf(px1, tx1);
        const float eh   = fmaxf(py2, ty2) - fminf(py1, ty1);
        const float ea   = ew * eh;
        const float giou = iou - (ea - uni) * __builtin_amdgcn_rcpf(ea);

        // cost = 5*L1 - prob - 2*giou   (nprob already negated)
        op[r * T] = fmaf(5.0f, l1, nprb) - 2.0f * giou;
    }
}

extern "C" void kernel_launch(void* const* d_in, const int* in_sizes, int n_in,
                              void* d_out, int out_size, void* d_ws, size_t ws_size,
                              hipStream_t stream) {
    const float* logits = (const float*)d_in[0];   // [B,Q,C]
    const float* pboxes = (const float*)d_in[1];   // [B,Q,4]
    const int*   labels = (const int*)d_in[2];     // [T]
    const float* tboxes = (const float*)d_in[3];   // [T,4]
    float* out   = (float*)d_out;
    float* nprob = (float*)d_ws;                   // [BQ, 92] = 5.3 MB

    const int T  = in_sizes[2];        // 1600
    const int BQ = in_sizes[1] / 4;    // 14400

    softmax_kernel<<<BQ / ROWS_A, 256, 0, stream>>>(logits, nprob);

    dim3 grid(T / 64, BQ / RR);        // (25, 450)
    cost_kernel<<<grid, 256, 0, stream>>>(pboxes, labels, tboxes, nprob, out, T);
}